// Round 2
// baseline (1139.640 us; speedup 1.0000x reference)
//
#include <hip/hip_runtime.h>
#include <math.h>

// ---------- Problem constants ----------
#define N_NODES 65536
#define B_GR    8
#define EMB_N   512
#define E_EDGES 458752     // N * 7
#define NSEG    458752     // N * 7 segments (row*7 + etype)
#define TSTRIDE 288        // per-type padded K (263 used: 256 feat + 7 onehot)
#define GK      2016       // 7 * 288, multiple of 32
#define ASTRIDE 296        // As row stride in u16 (148 words -> bank-even 8-way)
#define EPS     1e-5f

typedef unsigned short u16;
typedef unsigned int   u32;
typedef __bf16 bf16x8 __attribute__((ext_vector_type(8)));
typedef float  f32x4  __attribute__((ext_vector_type(4)));
typedef u16    u16x8  __attribute__((ext_vector_type(8)));

__device__ __forceinline__ float bf2f(u16 u) {
    u32 x = ((u32)u) << 16; float f; __builtin_memcpy(&f, &x, 4); return f;
}
__device__ __forceinline__ u16 f2bf(float f) {
    u32 x; __builtin_memcpy(&x, &f, 4);
    u32 r = x + 0x7fffu + ((x >> 16) & 1u);
    return (u16)(r >> 16);
}

// ---------- shared device bodies ----------
__device__ __forceinline__ void stats_body(int nb, int tid, const float* __restrict__ xin,
                                           const int* __restrict__ batch_id,
                                           float* __restrict__ S, float* __restrict__ Q) {
    int c = tid;
    int n0 = nb * 64;
    float s = 0.f, q = 0.f;
    int bcur = batch_id[n0];
    for (int r = 0; r < 64; r++) {
        int n = n0 + r;
        int b = batch_id[n];
        if (b != bcur) {
            atomicAdd(&S[bcur * 256 + c], s);
            atomicAdd(&Q[bcur * 256 + c], q);
            s = 0.f; q = 0.f; bcur = b;
        }
        float v = xin[(size_t)n * 256 + c];
        s += v;
        q = fmaf(v, v, q);
    }
    atomicAdd(&S[bcur * 256 + c], s);
    atomicAdd(&Q[bcur * 256 + c], q);
}

// norm + affine + SiLU with INLINE group-stat finalize (replaces finalize_kernel):
// each block recomputes the 256 (b,g) mean/istd pairs from S/Q/cnt (L2-cached).
__device__ __forceinline__ void norm_body(int nb, int tid, const float* __restrict__ xin,
                                          const int* __restrict__ batch_id,
                                          const float* __restrict__ S, const float* __restrict__ Q,
                                          const int* __restrict__ cnt,
                                          const float* __restrict__ w, const float* __restrict__ bias,
                                          u16* __restrict__ yout) {
    __shared__ float smean[256], sistd[256];
    {
        int b = tid >> 5, g = tid & 31;
        float Sg = 0.f, Qg = 0.f;
#pragma unroll
        for (int k = 0; k < 8; k++) {
            Sg += S[b * 256 + g * 8 + k];
            Qg += Q[b * 256 + g * 8 + k];
        }
        float cnt8 = (float)cnt[b] * 8.f;
        float D = cnt8 + EPS;                  // matches reference: count*cpg + EPS
        float m = Sg / D;
        float var = (Qg - 2.f * m * Sg + cnt8 * m * m) / D;
        smean[tid] = m;
        sistd[tid] = rsqrtf(var + EPS);
    }
    __syncthreads();
    int n = nb * 8 + (tid >> 5);
    int g = tid & 31;
    int c0 = g * 8;
    int b = batch_id[n];
    float m = smean[b * 32 + g], is = sistd[b * 32 + g];
    u16x8 o;
#pragma unroll
    for (int k = 0; k < 8; k++) {
        float v = (xin[(size_t)n * 256 + c0 + k] - m) * is;
        v = v * w[c0 + k] + bias[c0 + k];
        v = v / (1.f + __expf(-v));
        o[k] = f2bf(v);
    }
    *(u16x8*)&yout[(size_t)n * 256 + c0] = o;
}

// ---------- K1: count + weight transpose + emb GEMM + stats1 (fused front) ----------
__global__ __launch_bounds__(256) void front_kernel(
    const int* __restrict__ batch_id, int* __restrict__ cnt,
    const float* __restrict__ w1, const float* __restrict__ w2,
    u16* __restrict__ Wt1, u16* __restrict__ Wt2,
    const float* __restrict__ emb, const float* __restrict__ embw,
    const float* __restrict__ embb, float* __restrict__ embout,
    const float* __restrict__ x, float* __restrict__ S, float* __restrict__ Q)
{
    int bid = blockIdx.x, tid = threadIdx.x;
    if (bid < 256) {
        // per-batch node counts via wave ballot
        int i = bid * 256 + tid;
        int b = batch_id[i];
#pragma unroll
        for (int bb = 0; bb < 8; bb++) {
            unsigned long long mm = __ballot(b == bb);
            if ((tid & 63) == 0 && mm) atomicAdd(&cnt[bb], (int)__popcll(mm));
        }
    } else if (bid < 1264) {
        // weight transpose+pad (f32 -> bf16), 32x32 LDS tiles, coalesced both sides
        int r = bid - 256;
        const float* Win = (r < 504) ? w1 : w2;
        u16* Wt = (r < 504) ? Wt1 : Wt2;
        r %= 504;
        int t  = r / 72;
        int r2 = r % 72;
        int cc0 = (r2 / 8) * 32;       // 9 c-tiles cover padded 0..287
        int n0  = (r2 % 8) * 32;
        __shared__ float tile[32][33];
        int cl = tid & 31, rh = tid >> 5;
#pragma unroll
        for (int rr = 0; rr < 4; rr++) {
            int c = cc0 + rh + rr * 8;
            float v = 0.f;
            if (c < 263) v = Win[(size_t)(t * 263 + c) * 256 + n0 + cl];
            tile[rh + rr * 8][cl] = v;
        }
        __syncthreads();
#pragma unroll
        for (int rr = 0; rr < 4; rr++) {
            int n = n0 + rh + rr * 8;
            Wt[(size_t)n * GK + t * TSTRIDE + cc0 + cl] = f2bf(tile[cl][rh + rr * 8]);
        }
    } else if (bid == 1264) {
        // emb: silu(emb) @ embw + embb -> embout [8,256]
        __shared__ float semb[B_GR * EMB_N];
        for (int i = tid; i < B_GR * EMB_N; i += 256) {
            float e = emb[i];
            semb[i] = e / (1.f + __expf(-e));
        }
        __syncthreads();
        float acc[8];
        float bb = embb[tid];
#pragma unroll
        for (int b = 0; b < 8; b++) acc[b] = bb;
        for (int k = 0; k < EMB_N; k++) {
            float wv = embw[k * 256 + tid];
#pragma unroll
            for (int b = 0; b < 8; b++) acc[b] += semb[b * EMB_N + k] * wv;
        }
#pragma unroll
        for (int b = 0; b < 8; b++) embout[b * 256 + tid] = acc[b];
    } else {
        stats_body(bid - 1265, tid, x, batch_id, S, Q);
    }
}

// ---------- K2: hist + norm1 (fused) ----------
__global__ __launch_bounds__(256) void hist_norm_kernel(
    const int* __restrict__ ei, const int* __restrict__ et, int* __restrict__ hist,
    const float* __restrict__ xin, const int* __restrict__ batch_id,
    const float* __restrict__ S, const float* __restrict__ Q, const int* __restrict__ cnt,
    const float* __restrict__ w, const float* __restrict__ bias, u16* __restrict__ yout)
{
    int bid = blockIdx.x;
    if (bid < 1792) {
        int e = bid * 256 + threadIdx.x;   // 1792*256 == E_EDGES exactly
        int s = ei[e] * 7 + et[e];
        atomicAdd(&hist[s], 1);
    } else {
        norm_body(bid - 1792, threadIdx.x, xin, batch_id, S, Q, cnt, w, bias, yout);
    }
}

// ---------- standalone stats2 / norm2 ----------
__global__ __launch_bounds__(256) void stats_kernel(const float* __restrict__ xin,
                                                    const int* __restrict__ batch_id,
                                                    float* __restrict__ S, float* __restrict__ Q) {
    stats_body(blockIdx.x, threadIdx.x, xin, batch_id, S, Q);
}
__global__ __launch_bounds__(256) void norm_kernel(const float* __restrict__ xin,
                                                   const int* __restrict__ batch_id,
                                                   const float* __restrict__ S, const float* __restrict__ Q,
                                                   const int* __restrict__ cnt,
                                                   const float* __restrict__ w, const float* __restrict__ bias,
                                                   u16* __restrict__ yout) {
    norm_body(blockIdx.x, threadIdx.x, xin, batch_id, S, Q, cnt, w, bias, yout);
}

// ---------- CSR scans ----------
__global__ __launch_bounds__(512) void scan1_kernel(const int* __restrict__ hist, int* __restrict__ partials) {
    __shared__ int sd[512];
    int i = blockIdx.x * 512 + threadIdx.x;
    sd[threadIdx.x] = hist[i];
    __syncthreads();
    for (int off = 256; off > 0; off >>= 1) {
        if (threadIdx.x < off) sd[threadIdx.x] += sd[threadIdx.x + off];
        __syncthreads();
    }
    if (threadIdx.x == 0) partials[blockIdx.x] = sd[0];
}

__global__ __launch_bounds__(1024) void scan2_kernel(int* __restrict__ partials) {
    __shared__ int sd[1024];
    int t = threadIdx.x;
    int v = (t < 896) ? partials[t] : 0;
    sd[t] = v;
    __syncthreads();
    for (int off = 1; off < 1024; off <<= 1) {
        int u = (t >= off) ? sd[t - off] : 0;
        __syncthreads();
        sd[t] += u;
        __syncthreads();
    }
    if (t < 896) partials[t] = sd[t] - v;   // exclusive
}

__global__ __launch_bounds__(512) void scan3_kernel(int* __restrict__ hist_offs, const int* __restrict__ partials,
                                                    int* __restrict__ cursor) {
    __shared__ int sd[512];
    int t = threadIdx.x;
    int i = blockIdx.x * 512 + t;
    int c = hist_offs[i];
    sd[t] = c;
    __syncthreads();
    for (int off = 1; off < 512; off <<= 1) {
        int u = (t >= off) ? sd[t - off] : 0;
        __syncthreads();
        sd[t] += u;
        __syncthreads();
    }
    int o = partials[blockIdx.x] + sd[t] - c;
    hist_offs[i] = o;
    cursor[i] = o;
}

// ---------- K6: fill elist + re-zero S/Q for GN2 ----------
__global__ __launch_bounds__(256) void fill_zero_kernel(const int* __restrict__ ei, const int* __restrict__ et,
                                                        int* __restrict__ cursor, int* __restrict__ elist,
                                                        float* __restrict__ S, float* __restrict__ Q) {
    int bid = blockIdx.x;
    if (bid < 1792) {
        int e = bid * 256 + threadIdx.x;
        int s = ei[e] * 7 + et[e];
        int p = atomicAdd(&cursor[s], 1);
        if (p >= 0 && p < E_EDGES) elist[p] = ei[E_EDGES + e];   // col
    } else {
        int i = (bid - 1792) * 256 + threadIdx.x;   // 8*256 == 2048 exactly
        S[i] = 0.f; Q[i] = 0.f;
    }
}

// ---------- fused aggregate + MFMA GEMM: per-TYPE phase structure ----------
// Per type t (K=288): phase A waits ONCE on the gathers issued during the
// previous type's phase B, folds in f32, writes the full 64x288 A-panel to
// LDS (row stride 296 u16 -> even 8-way banks); phase B runs 9 chunks of
// {a-frag ds_read, 8 MFMA} back-to-back with B in a 3-deep L2 register ring
// (slot c9%3; 9%3==0 keeps slot parity across types). Next-type CSR is
// pipelined inside phase B: offs/cursor @c9==0, elist cols @c9==2, y-gathers
// + node_type @c9==5 (~600cyc slack before the single phase-A wait).
// Edge overflow: cols c2/c3 prefetched (covers cnt<=4, 98%); their y-gathers
// issue at phase-A top overlapping the fold; cnt>=5 (0.4%) serial.
// mode 0: out = acc + embout[batch_id[m]][n]   (h2 f32, in d_out)
// mode 1: out = acc + x[m][n]                  (final f32 output)
__global__ __launch_bounds__(512, 4) void gemm_fused_kernel(
    const u16* __restrict__ y, const u16* __restrict__ Bt,
    const int* __restrict__ offs, const int* __restrict__ cursor,
    const int* __restrict__ elist, const int* __restrict__ node_type,
    const int* __restrict__ batch_id, const float* __restrict__ embout,
    const float* __restrict__ xres, float* __restrict__ out, int mode)
{
    __shared__ __align__(16) u16 As[64 * ASTRIDE];   // 37.9 KB, single buffer
    int tid = threadIdx.x;
    int lane = tid & 63;
    int wn = tid >> 6;                 // 8 waves, each 64(m) x 32(n)
    int lm = lane & 15, lq = lane >> 4;
    int m0 = blockIdx.x * 64;
    int ar = tid >> 3;                 // gather row 0..63
    int tq = tid & 7;                  // 32-channel chunk 0..7
    const size_t yq = (size_t)tq * 32;

    f32x4 acc[4][2];
    f32x4 zz = {0.f, 0.f, 0.f, 0.f};
#pragma unroll
    for (int i = 0; i < 4; i++)
#pragma unroll
        for (int j = 0; j < 2; j++) acc[i][j] = zz;

    const u16* btp0 = Bt + (size_t)(wn * 32 + lm) * GK + lq * 8;
    const u16* btp1 = btp0 + (size_t)16 * GK;

    int sbase = (m0 + ar) * 7;

    // ---- prologue: type-0 CSR + gathers + B chunks 0..2 ----
    int st = offs[sbase], en = cursor[sbase];
    int c0 = (st     < en) ? elist[st]     : -1;
    int c1 = (st + 1 < en) ? elist[st + 1] : -1;
    int c2 = (st + 2 < en) ? elist[st + 2] : -1;
    int c3 = (st + 3 < en) ? elist[st + 3] : -1;
    int nt0 = -1, nt1 = -1;
    u16x8 e0[4], e1[4];
    if (c0 >= 0) {
#pragma unroll
        for (int q = 0; q < 4; q++) e0[q] = *(const u16x8*)&y[(size_t)c0 * 256 + yq + q * 8];
    }
    if (c1 >= 0) {
#pragma unroll
        for (int q = 0; q < 4; q++) e1[q] = *(const u16x8*)&y[(size_t)c1 * 256 + yq + q * 8];
    }
    if (tq == 0) {
        if (c0 >= 0) nt0 = node_type[c0];
        if (c1 >= 0) nt1 = node_type[c1];
    }
    bf16x8 bR[3][2];
#pragma unroll
    for (int p = 0; p < 3; p++) {
        bR[p][0] = *(const bf16x8*)&btp0[p * 32];
        bR[p][1] = *(const bf16x8*)&btp1[p * 32];
    }

    int stn = 0, enn = 0, c0n = -1, c1n = -1, c2n = -1, c3n = -1, nt0n = -1, nt1n = -1;

    for (int t = 0; t < 7; t++) {
        // ================= phase A =================
        int cnt = en - st;
        u16x8 x2[4], x3[4];
        int nt2 = -1, nt3 = -1;
        if (c2 >= 0) {
#pragma unroll
            for (int q = 0; q < 4; q++) x2[q] = *(const u16x8*)&y[(size_t)c2 * 256 + yq + q * 8];
            if (tq == 0) nt2 = node_type[c2];
        }
        if (c3 >= 0) {
#pragma unroll
            for (int q = 0; q < 4; q++) x3[q] = *(const u16x8*)&y[(size_t)c3 * 256 + yq + q * 8];
            if (tq == 0) nt3 = node_type[c3];
        }
        float s[4][8];
#pragma unroll
        for (int q = 0; q < 4; q++)
#pragma unroll
            for (int j = 0; j < 8; j++) {
                float v = 0.f;
                if (c0 >= 0) v += bf2f(e0[q][j]);
                if (c1 >= 0) v += bf2f(e1[q][j]);
                s[q][j] = v;
            }
        if (c2 >= 0) {
#pragma unroll
            for (int q = 0; q < 4; q++)
#pragma unroll
                for (int j = 0; j < 8; j++) s[q][j] += bf2f(x2[q][j]);
        }
        if (c3 >= 0) {
#pragma unroll
            for (int q = 0; q < 4; q++)
#pragma unroll
                for (int j = 0; j < 8; j++) s[q][j] += bf2f(x3[q][j]);
        }
        float oh[7];
        if (tq == 0) {
#pragma unroll
            for (int j = 0; j < 7; j++)
                oh[j] = (nt0 == j ? 1.f : 0.f) + (nt1 == j ? 1.f : 0.f)
                      + (nt2 == j ? 1.f : 0.f) + (nt3 == j ? 1.f : 0.f);
        }
        if (cnt > 4) {          // rare (~0.4% of segments)
            for (int e = st + 4; e < en; e++) {
                int c = elist[e];
                u16x8 r[4];
#pragma unroll
                for (int q = 0; q < 4; q++) r[q] = *(const u16x8*)&y[(size_t)c * 256 + yq + q * 8];
#pragma unroll
                for (int q = 0; q < 4; q++)
#pragma unroll
                    for (int j = 0; j < 8; j++) s[q][j] += bf2f(r[q][j]);
                if (tq == 0) {
                    int nt = node_type[c];
#pragma unroll
                    for (int j = 0; j < 7; j++) oh[j] += (nt == j) ? 1.f : 0.f;
                }
            }
        }
        __syncthreads();        // all waves done reading As (previous type)
#pragma unroll
        for (int q = 0; q < 4; q++) {
            u16x8 w;
#pragma unroll
            for (int j = 0; j < 8; j++) w[j] = f2bf(s[q][j]);
            *(u16x8*)&As[ar * ASTRIDE + tq * 32 + q * 8] = w;
        }
        if (tq == 0) {
            u16x8 w, z;
#pragma unroll
            for (int j = 0; j < 8; j++) { w[j] = 0; z[j] = 0; }
#pragma unroll
            for (int j = 0; j < 7; j++) w[j] = f2bf(oh[j]);
            *(u16x8*)&As[ar * ASTRIDE + 256] = w;
            *(u16x8*)&As[ar * ASTRIDE + 264] = z;
            *(u16x8*)&As[ar * ASTRIDE + 272] = z;
            *(u16x8*)&As[ar * ASTRIDE + 280] = z;
        }
        __syncthreads();        // As panel ready
        // ================= phase B =================
#pragma unroll
        for (int c9 = 0; c9 < 9; c9++) {
            bf16x8 a[4];
#pragma unroll
            for (int i = 0; i < 4; i++)
                a[i] = *(const bf16x8*)&As[(i * 16 + lm) * ASTRIDE + c9 * 32 + lq * 8];
            // B prefetch chunk c9+3 (same slot c9%3, SSA-renamed via temps)
            bf16x8 bn0, bn1;
            const bool doB = (t < 6) || (c9 < 6);
            if (doB) {
                int kb = t * TSTRIDE + (c9 + 3) * 32;   // ==(t+1)*288+(c9-6)*32 for c9>=6
                bn0 = *(const bf16x8*)&btp0[kb];
                bn1 = *(const bf16x8*)&btp1[kb];
            }
            // next-type CSR pipeline
            if (t < 6) {
                if (c9 == 0) { stn = offs[sbase + t + 1]; enn = cursor[sbase + t + 1]; }
                if (c9 == 2) {
                    c0n = (stn     < enn) ? elist[stn]     : -1;
                    c1n = (stn + 1 < enn) ? elist[stn + 1] : -1;
                    c2n = (stn + 2 < enn) ? elist[stn + 2] : -1;
                    c3n = (stn + 3 < enn) ? elist[stn + 3] : -1;
                }
                if (c9 == 5) {
                    if (c0n >= 0) {
#pragma unroll
                        for (int q = 0; q < 4; q++) e0[q] = *(const u16x8*)&y[(size_t)c0n * 256 + yq + q * 8];
                    }
                    if (c1n >= 0) {
#pragma unroll
                        for (int q = 0; q < 4; q++) e1[q] = *(const u16x8*)&y[(size_t)c1n * 256 + yq + q * 8];
                    }
                    if (tq == 0) {
                        nt0n = (c0n >= 0) ? node_type[c0n] : -1;
                        nt1n = (c1n >= 0) ? node_type[c1n] : -1;
                    }
                }
            }
            // MFMA
            __builtin_amdgcn_s_setprio(1);
#pragma unroll
            for (int i = 0; i < 4; i++) {
                acc[i][0] = __builtin_amdgcn_mfma_f32_16x16x32_bf16(a[i], bR[c9 % 3][0], acc[i][0], 0, 0, 0);
                acc[i][1] = __builtin_amdgcn_mfma_f32_16x16x32_bf16(a[i], bR[c9 % 3][1], acc[i][1], 0, 0, 0);
            }
            __builtin_amdgcn_s_setprio(0);
            if (doB) { bR[c9 % 3][0] = bn0; bR[c9 % 3][1] = bn1; }
        }
        // rotate next -> current (e0/e1 already loaded in place)
        st = stn; en = enn;
        c0 = c0n; c1 = c1n; c2 = c2n; c3 = c3n;
        nt0 = nt0n; nt1 = nt1n;
    }

    // ---- epilogue ----
#pragma unroll
    for (int i = 0; i < 4; i++) {
#pragma unroll
        for (int r = 0; r < 4; r++) {
            size_t m = (size_t)m0 + i * 16 + lq * 4 + r;
            float addv[2];
            if (mode == 0) {
                int b = batch_id[m];
#pragma unroll
                for (int j = 0; j < 2; j++) addv[j] = embout[b * 256 + wn * 32 + j * 16 + lm];
            } else {
#pragma unroll
                for (int j = 0; j < 2; j++) addv[j] = xres[m * 256 + wn * 32 + j * 16 + lm];
            }
#pragma unroll
            for (int j = 0; j < 2; j++) {
                int n = wn * 32 + j * 16 + lm;
                out[m * 256 + n] = acc[i][j][r] + addv[j];
            }
        }
    }
}

// ---------- host ----------
extern "C" void kernel_launch(void* const* d_in, const int* in_sizes, int n_in,
                              void* d_out, int out_size, void* d_ws, size_t ws_size,
                              hipStream_t stream) {
    const float* x    = (const float*)d_in[0];
    const float* emb  = (const float*)d_in[1];
    const int* bid    = (const int*)d_in[2];
    const int* ei     = (const int*)d_in[3];
    const int* et     = (const int*)d_in[4];
    const int* ntp    = (const int*)d_in[5];
    const float* gn1w = (const float*)d_in[6];
    const float* gn1b = (const float*)d_in[7];
    const float* w1   = (const float*)d_in[8];
    const float* embw = (const float*)d_in[9];
    const float* embb = (const float*)d_in[10];
    const float* gn2w = (const float*)d_in[11];
    const float* gn2b = (const float*)d_in[12];
    const float* w2   = (const float*)d_in[13];
    float* out = (float*)d_out;

    char* p = (char*)d_ws;
    size_t off = 0;
    auto nxt = [&](size_t bytes) -> void* {
        void* r = p + off;
        off += (bytes + 255) & ~(size_t)255;
        return r;
    };
    u16*   y       = (u16*)nxt((size_t)N_NODES * 256 * 2);     // 33.5 MB (bf16 stage)
    u16*   Wt1     = (u16*)nxt((size_t)256 * GK * 2);          // 1.03 MB
    u16*   Wt2     = (u16*)nxt((size_t)256 * GK * 2);          // 1.03 MB
    float* embout  = (float*)nxt(8 * 256 * 4);
    float* S       = (float*)nxt(2048 * 4);                    // S,Q,cnt contiguous
    float* Q       = (float*)nxt(2048 * 4);                    //   -> one memset
    int*   cnt     = (int*)nxt(8 * 4);
    int*   offs    = (int*)nxt((size_t)NSEG * 4);              // hist, then offsets in place
    int*   cursor  = (int*)nxt((size_t)NSEG * 4);
    int*   parts   = (int*)nxt(1024 * 4);
    int*   elist   = (int*)nxt((size_t)E_EDGES * 4);
    float* h2      = out;   // d_out doubles as h2 (dead before final write)
    (void)ws_size; (void)in_sizes; (void)n_in; (void)out_size;

    // zero scratch (graph-capture-safe async memsets)
    hipMemsetAsync(offs, 0, (size_t)NSEG * 4, stream);
    hipMemsetAsync(S, 0, 8192 + 8192 + 256, stream);           // S + Q + cnt
    // K1: count + weight transpose + emb GEMM + GN1 stats
    front_kernel<<<2289, 256, 0, stream>>>(bid, cnt, w1, w2, Wt1, Wt2,
                                           emb, embw, embb, embout, x, S, Q);
    // K2: hist + GN1 norm/SiLU (inline finalize) -> y
    hist_norm_kernel<<<9984, 256, 0, stream>>>(ei, et, offs, x, bid, S, Q, cnt, gn1w, gn1b, y);
    // K3-K5: CSR scans
    scan1_kernel<<<896, 512, 0, stream>>>(offs, parts);
    scan2_kernel<<<1, 1024, 0, stream>>>(parts);
    scan3_kernel<<<896, 512, 0, stream>>>(offs, parts, cursor);
    // K6: fill elist + re-zero S/Q
    fill_zero_kernel<<<1800, 256, 0, stream>>>(ei, et, cursor, elist, S, Q);
    // K7: conv1 fused aggregate+GEMM(+emb) -> h2 (in d_out)
    gemm_fused_kernel<<<1024, 512, 0, stream>>>(y, Wt1, offs, cursor, elist, ntp, bid, embout, x, h2, 0);
    // K8-K9: GN2 stats + norm/SiLU -> y
    stats_kernel<<<1024, 256, 0, stream>>>(h2, bid, S, Q);
    norm_kernel<<<8192, 256, 0, stream>>>(h2, bid, S, Q, cnt, gn2w, gn2b, y);
    // K10: conv2 fused aggregate+GEMM(+x skip) -> out
    gemm_fused_kernel<<<1024, 512, 0, stream>>>(y, Wt2, offs, cursor, elist, ntp, bid, embout, x, out, 1);
}

// Round 3
// 749.612 us; speedup vs baseline: 1.5203x; 1.5203x over previous
//
#include <hip/hip_runtime.h>
#include <math.h>

// ---------- Problem constants ----------
#define N_NODES 65536
#define B_GR    8
#define EMB_N   512
#define E_EDGES 458752     // N * 7
#define NSEG    458752     // N * 7 segments (row*7 + etype)
#define TSTRIDE 288        // per-type padded K (263 used: 256 feat + 7 onehot)
#define GK      2016       // 7 * 288, multiple of 32
#define EPS     1e-5f

typedef unsigned short u16;
typedef unsigned int   u32;
typedef __bf16 bf16x8 __attribute__((ext_vector_type(8)));
typedef float  f32x4  __attribute__((ext_vector_type(4)));
typedef u16    u16x8  __attribute__((ext_vector_type(8)));

__device__ __forceinline__ float bf2f(u16 u) {
    u32 x = ((u32)u) << 16; float f; __builtin_memcpy(&f, &x, 4); return f;
}
__device__ __forceinline__ u16 f2bf(float f) {
    u32 x; __builtin_memcpy(&x, &f, 4);
    u32 r = x + 0x7fffu + ((x >> 16) & 1u);
    return (u16)(r >> 16);
}

// ---------- shared device bodies ----------
__device__ __forceinline__ void stats_body(int nb, int tid, const float* __restrict__ xin,
                                           const int* __restrict__ batch_id,
                                           float* __restrict__ S, float* __restrict__ Q) {
    int c = tid;
    int n0 = nb * 64;
    float s = 0.f, q = 0.f;
    int bcur = batch_id[n0];
    for (int r = 0; r < 64; r++) {
        int n = n0 + r;
        int b = batch_id[n];
        if (b != bcur) {
            atomicAdd(&S[bcur * 256 + c], s);
            atomicAdd(&Q[bcur * 256 + c], q);
            s = 0.f; q = 0.f; bcur = b;
        }
        float v = xin[(size_t)n * 256 + c];
        s += v;
        q = fmaf(v, v, q);
    }
    atomicAdd(&S[bcur * 256 + c], s);
    atomicAdd(&Q[bcur * 256 + c], q);
}

// norm + affine + SiLU with inline group-stat finalize:
// each block recomputes the 256 (b,g) mean/istd pairs from S/Q/cnt (L2-cached).
__device__ __forceinline__ void norm_body(int nb, int tid, const float* __restrict__ xin,
                                          const int* __restrict__ batch_id,
                                          const float* __restrict__ S, const float* __restrict__ Q,
                                          const int* __restrict__ cnt,
                                          const float* __restrict__ w, const float* __restrict__ bias,
                                          u16* __restrict__ yout) {
    __shared__ float smean[256], sistd[256];
    {
        int b = tid >> 5, g = tid & 31;
        float Sg = 0.f, Qg = 0.f;
#pragma unroll
        for (int k = 0; k < 8; k++) {
            Sg += S[b * 256 + g * 8 + k];
            Qg += Q[b * 256 + g * 8 + k];
        }
        float cnt8 = (float)cnt[b] * 8.f;
        float D = cnt8 + EPS;                  // matches reference: count*cpg + EPS
        float m = Sg / D;
        float var = (Qg - 2.f * m * Sg + cnt8 * m * m) / D;
        smean[tid] = m;
        sistd[tid] = rsqrtf(var + EPS);
    }
    __syncthreads();
    int n = nb * 8 + (tid >> 5);
    int g = tid & 31;
    int c0 = g * 8;
    int b = batch_id[n];
    float m = smean[b * 32 + g], is = sistd[b * 32 + g];
    u16x8 o;
#pragma unroll
    for (int k = 0; k < 8; k++) {
        float v = (xin[(size_t)n * 256 + c0 + k] - m) * is;
        v = v * w[c0 + k] + bias[c0 + k];
        v = v / (1.f + __expf(-v));
        o[k] = f2bf(v);
    }
    *(u16x8*)&yout[(size_t)n * 256 + c0] = o;
}

// ---------- K1: count + weight transpose + emb GEMM + stats1 (fused front) ----------
__global__ __launch_bounds__(256) void front_kernel(
    const int* __restrict__ batch_id, int* __restrict__ cnt,
    const float* __restrict__ w1, const float* __restrict__ w2,
    u16* __restrict__ Wt1, u16* __restrict__ Wt2,
    const float* __restrict__ emb, const float* __restrict__ embw,
    const float* __restrict__ embb, float* __restrict__ embout,
    const float* __restrict__ x, float* __restrict__ S, float* __restrict__ Q)
{
    int bid = blockIdx.x, tid = threadIdx.x;
    if (bid < 256) {
        int i = bid * 256 + tid;
        int b = batch_id[i];
#pragma unroll
        for (int bb = 0; bb < 8; bb++) {
            unsigned long long mm = __ballot(b == bb);
            if ((tid & 63) == 0 && mm) atomicAdd(&cnt[bb], (int)__popcll(mm));
        }
    } else if (bid < 1264) {
        // weight transpose+pad (f32 -> bf16), 32x32 LDS tiles, coalesced both sides
        int r = bid - 256;
        const float* Win = (r < 504) ? w1 : w2;
        u16* Wt = (r < 504) ? Wt1 : Wt2;
        r %= 504;
        int t  = r / 72;
        int r2 = r % 72;
        int cc0 = (r2 / 8) * 32;       // 9 c-tiles cover padded 0..287
        int n0  = (r2 % 8) * 32;
        __shared__ float tile[32][33];
        int cl = tid & 31, rh = tid >> 5;
#pragma unroll
        for (int rr = 0; rr < 4; rr++) {
            int c = cc0 + rh + rr * 8;
            float v = 0.f;
            if (c < 263) v = Win[(size_t)(t * 263 + c) * 256 + n0 + cl];
            tile[rh + rr * 8][cl] = v;
        }
        __syncthreads();
#pragma unroll
        for (int rr = 0; rr < 4; rr++) {
            int n = n0 + rh + rr * 8;
            Wt[(size_t)n * GK + t * TSTRIDE + cc0 + cl] = f2bf(tile[cl][rh + rr * 8]);
        }
    } else if (bid == 1264) {
        __shared__ float semb[B_GR * EMB_N];
        for (int i = tid; i < B_GR * EMB_N; i += 256) {
            float e = emb[i];
            semb[i] = e / (1.f + __expf(-e));
        }
        __syncthreads();
        float acc[8];
        float bb = embb[tid];
#pragma unroll
        for (int b = 0; b < 8; b++) acc[b] = bb;
        for (int k = 0; k < EMB_N; k++) {
            float wv = embw[k * 256 + tid];
#pragma unroll
            for (int b = 0; b < 8; b++) acc[b] += semb[b * EMB_N + k] * wv;
        }
#pragma unroll
        for (int b = 0; b < 8; b++) embout[b * 256 + tid] = acc[b];
    } else {
        stats_body(bid - 1265, tid, x, batch_id, S, Q);
    }
}

// ---------- K2: hist + norm1 (fused) ----------
__global__ __launch_bounds__(256) void hist_norm_kernel(
    const int* __restrict__ ei, const int* __restrict__ et, int* __restrict__ hist,
    const float* __restrict__ xin, const int* __restrict__ batch_id,
    const float* __restrict__ S, const float* __restrict__ Q, const int* __restrict__ cnt,
    const float* __restrict__ w, const float* __restrict__ bias, u16* __restrict__ yout)
{
    int bid = blockIdx.x;
    if (bid < 1792) {
        int e = bid * 256 + threadIdx.x;   // 1792*256 == E_EDGES exactly
        int s = ei[e] * 7 + et[e];
        atomicAdd(&hist[s], 1);
    } else {
        norm_body(bid - 1792, threadIdx.x, xin, batch_id, S, Q, cnt, w, bias, yout);
    }
}

// ---------- standalone stats2 / norm2 ----------
__global__ __launch_bounds__(256) void stats_kernel(const float* __restrict__ xin,
                                                    const int* __restrict__ batch_id,
                                                    float* __restrict__ S, float* __restrict__ Q) {
    stats_body(blockIdx.x, threadIdx.x, xin, batch_id, S, Q);
}
__global__ __launch_bounds__(256) void norm_kernel(const float* __restrict__ xin,
                                                   const int* __restrict__ batch_id,
                                                   const float* __restrict__ S, const float* __restrict__ Q,
                                                   const int* __restrict__ cnt,
                                                   const float* __restrict__ w, const float* __restrict__ bias,
                                                   u16* __restrict__ yout) {
    norm_body(blockIdx.x, threadIdx.x, xin, batch_id, S, Q, cnt, w, bias, yout);
}

// ---------- CSR scans ----------
__global__ __launch_bounds__(512) void scan1_kernel(const int* __restrict__ hist, int* __restrict__ partials) {
    __shared__ int sd[512];
    int i = blockIdx.x * 512 + threadIdx.x;
    sd[threadIdx.x] = hist[i];
    __syncthreads();
    for (int off = 256; off > 0; off >>= 1) {
        if (threadIdx.x < off) sd[threadIdx.x] += sd[threadIdx.x + off];
        __syncthreads();
    }
    if (threadIdx.x == 0) partials[blockIdx.x] = sd[0];
}

__global__ __launch_bounds__(1024) void scan2_kernel(int* __restrict__ partials) {
    __shared__ int sd[1024];
    int t = threadIdx.x;
    int v = (t < 896) ? partials[t] : 0;
    sd[t] = v;
    __syncthreads();
    for (int off = 1; off < 1024; off <<= 1) {
        int u = (t >= off) ? sd[t - off] : 0;
        __syncthreads();
        sd[t] += u;
        __syncthreads();
    }
    if (t < 896) partials[t] = sd[t] - v;   // exclusive
}

__global__ __launch_bounds__(512) void scan3_kernel(int* __restrict__ hist_offs, const int* __restrict__ partials,
                                                    int* __restrict__ cursor) {
    __shared__ int sd[512];
    int t = threadIdx.x;
    int i = blockIdx.x * 512 + t;
    int c = hist_offs[i];
    sd[t] = c;
    __syncthreads();
    for (int off = 1; off < 512; off <<= 1) {
        int u = (t >= off) ? sd[t - off] : 0;
        __syncthreads();
        sd[t] += u;
        __syncthreads();
    }
    int o = partials[blockIdx.x] + sd[t] - c;
    hist_offs[i] = o;
    cursor[i] = o;
}

// ---------- K6: fill elist + re-zero S/Q for GN2 ----------
__global__ __launch_bounds__(256) void fill_zero_kernel(const int* __restrict__ ei, const int* __restrict__ et,
                                                        int* __restrict__ cursor, int* __restrict__ elist,
                                                        float* __restrict__ S, float* __restrict__ Q) {
    int bid = blockIdx.x;
    if (bid < 1792) {
        int e = bid * 256 + threadIdx.x;
        int s = ei[e] * 7 + et[e];
        int p = atomicAdd(&cursor[s], 1);
        if (p >= 0 && p < E_EDGES) elist[p] = ei[E_EDGES + e];   // col
    } else {
        int i = (bid - 1792) * 256 + threadIdx.x;   // 8*256 == 2048 exactly
        S[i] = 0.f; Q[i] = 0.f;
    }
}

// ---------- fused aggregate + MFMA GEMM: superchunk phases, low-register ----------
// 512 thr, 8 waves x (64m x 32n). Per type t (K=288): 4 superchunk phases
// (64 ch each, 16 MFMA) + 1 one-hot phase (32 ch, 8 MFMA) = 5 barriers/type.
// A-build: 8 threads/row (tq = channel octet); per edge one coalesced 128B
// line (8 x 16B). Gathers land in gv[4] (16 VGPR), folded f32 -> bf16 ->
// LDS at the NEXT phase top (prefetch distance ~1 phase; next-type gathers
// issue at sc3, 2 phases ahead). As[2][64][8 slots] double-buffered, slot
// XOR-swizzled (slot ^ (row&7)): writes 1024B contiguous/wave, frag reads
// hit all 32 banks (conflict-free). ONE barrier per phase.
// NO __launch_bounds__ reg cap: round 2's (512,4) cap spilled ~1GB scratch
// (WRITE_SIZE 684MB) -- never trade spills for occupancy.
// cols cached 4/segment (99.6%); cnt>=5 overflow serial at fold.
// mode 0: out = acc + embout[batch_id[m]][n]; mode 1: out = acc + x[m][n]
__global__ __launch_bounds__(512) void gemm_fused_kernel(
    const u16* __restrict__ y, const u16* __restrict__ Bt,
    const int* __restrict__ offs, const int* __restrict__ cursor,
    const int* __restrict__ elist, const int* __restrict__ node_type,
    const int* __restrict__ batch_id, const float* __restrict__ embout,
    const float* __restrict__ xres, float* __restrict__ out, int mode)
{
    __shared__ __align__(16) u16 As[2][64 * 64];   // 16 KB double-buffered
    int tid = threadIdx.x;
    int lane = tid & 63;
    int wn = tid >> 6;                 // 8 waves, each 64(m) x 32(n)
    int lm = lane & 15, lq = lane >> 4;
    int m0 = blockIdx.x * 64;
    int ar = tid >> 3;                 // gather row 0..63
    int tq = tid & 7;                  // channel octet 0..7

    f32x4 acc[4][2];
    f32x4 zz = {0.f, 0.f, 0.f, 0.f};
#pragma unroll
    for (int i = 0; i < 4; i++)
#pragma unroll
        for (int j = 0; j < 2; j++) acc[i][j] = zz;

    const u16* btp0 = Bt + (size_t)(wn * 32 + lm) * GK + lq * 8;
    const u16* btp1 = btp0 + (size_t)16 * GK;

    int sbase = (m0 + ar) * 7;

    // ---- prologue: type-0 CSR + sc0 gathers + B chunks 0,1 ----
    int st = offs[sbase], en = cursor[sbase];
    int col[4];
#pragma unroll
    for (int u = 0; u < 4; u++) col[u] = (st + u < en) ? elist[st + u] : -1;
    u16x8 gv[4];
#pragma unroll
    for (int u = 0; u < 4; u++)
        if (col[u] >= 0) gv[u] = *(const u16x8*)&y[(size_t)col[u] * 256 + tq * 8];
    bf16x8 bcur[2][2];
#pragma unroll
    for (int k = 0; k < 2; k++) {
        bcur[k][0] = *(const bf16x8*)&btp0[k * 32];
        bcur[k][1] = *(const bf16x8*)&btp1[k * 32];
    }
    bf16x8 boh[2];
    int stn = 0, enn = 0;
    int coln[4] = {-1, -1, -1, -1};
    int nt4[4] = {-1, -1, -1, -1};
    int buf = 0;

    for (int t = 0; t < 7; t++) {
        // ========== 4 superchunk phases ==========
#pragma unroll
        for (int sc = 0; sc < 4; sc++) {
            // ---- fold gv (issued last phase) -> write As[buf] ----
            float f[8];
#pragma unroll
            for (int j = 0; j < 8; j++) f[j] = 0.f;
#pragma unroll
            for (int u = 0; u < 4; u++)
                if (col[u] >= 0) {
#pragma unroll
                    for (int j = 0; j < 8; j++) f[j] += bf2f(gv[u][j]);
                }
            if (en - st > 4) {          // rare (0.37% of segments)
                for (int e = st + 4; e < en; e++) {
                    u16x8 v = *(const u16x8*)&y[(size_t)elist[e] * 256 + sc * 64 + tq * 8];
#pragma unroll
                    for (int j = 0; j < 8; j++) f[j] += bf2f(v[j]);
                }
            }
            {
                u16x8 w8;
#pragma unroll
                for (int j = 0; j < 8; j++) w8[j] = f2bf(f[j]);
                *(u16x8*)&As[buf][ar * 64 + ((tq ^ (ar & 7)) * 8)] = w8;
            }
            __syncthreads();
            // ---- frag reads (both 32-chunks of this superchunk) ----
            bf16x8 a[2][4];
#pragma unroll
            for (int k = 0; k < 2; k++)
#pragma unroll
                for (int i = 0; i < 4; i++) {
                    int row = i * 16 + lm;
                    a[k][i] = *(const bf16x8*)&As[buf][row * 64 + (((k * 4 + lq) ^ (row & 7)) * 8)];
                }
            // ---- issue next-phase loads (overlap MFMA) ----
            bf16x8 bn00, bn01, bn10, bn11;
            if (sc < 3) {
                int cb = (sc + 1) * 64 + tq * 8;
#pragma unroll
                for (int u = 0; u < 4; u++)
                    if (col[u] >= 0) gv[u] = *(const u16x8*)&y[(size_t)col[u] * 256 + cb];
                int kb = t * TSTRIDE + (sc + 1) * 64;
                bn00 = *(const bf16x8*)&btp0[kb];
                bn01 = *(const bf16x8*)&btp1[kb];
                bn10 = *(const bf16x8*)&btp0[kb + 32];
                bn11 = *(const bf16x8*)&btp1[kb + 32];
                if (sc == 0 && t < 6) { stn = offs[sbase + t + 1]; enn = cursor[sbase + t + 1]; }
                if (sc == 1 && t < 6) {
#pragma unroll
                    for (int u = 0; u < 4; u++) coln[u] = (stn + u < enn) ? elist[stn + u] : -1;
                }
                if (sc == 2 && tq == 0) {
#pragma unroll
                    for (int u = 0; u < 4; u++) nt4[u] = (col[u] >= 0) ? node_type[col[u]] : -1;
                }
            } else {
                // sc==3: one-hot B + next-type sc0 gathers (2 phases ahead)
                int kb = t * TSTRIDE + 256;
                boh[0] = *(const bf16x8*)&btp0[kb];
                boh[1] = *(const bf16x8*)&btp1[kb];
                if (t < 6) {
#pragma unroll
                    for (int u = 0; u < 4; u++)
                        if (coln[u] >= 0) gv[u] = *(const u16x8*)&y[(size_t)coln[u] * 256 + tq * 8];
                }
            }
            // ---- 16 MFMA ----
            __builtin_amdgcn_s_setprio(1);
#pragma unroll
            for (int k = 0; k < 2; k++)
#pragma unroll
                for (int i = 0; i < 4; i++) {
                    acc[i][0] = __builtin_amdgcn_mfma_f32_16x16x32_bf16(a[k][i], bcur[k][0], acc[i][0], 0, 0, 0);
                    acc[i][1] = __builtin_amdgcn_mfma_f32_16x16x32_bf16(a[k][i], bcur[k][1], acc[i][1], 0, 0, 0);
                }
            __builtin_amdgcn_s_setprio(0);
            if (sc < 3) { bcur[0][0] = bn00; bcur[0][1] = bn01; bcur[1][0] = bn10; bcur[1][1] = bn11; }
            buf ^= 1;
        }
        // ========== one-hot phase (K=32) ==========
        {
            u16x8 w8;
#pragma unroll
            for (int j = 0; j < 8; j++) w8[j] = 0;
            if (tq == 0) {
                float oh[7];
#pragma unroll
                for (int j = 0; j < 7; j++)
                    oh[j] = (nt4[0] == j ? 1.f : 0.f) + (nt4[1] == j ? 1.f : 0.f)
                          + (nt4[2] == j ? 1.f : 0.f) + (nt4[3] == j ? 1.f : 0.f);
                if (en - st > 4) {
                    for (int e = st + 4; e < en; e++) {
                        int nt = node_type[elist[e]];
#pragma unroll
                        for (int j = 0; j < 7; j++) oh[j] += (nt == j) ? 1.f : 0.f;
                    }
                }
#pragma unroll
                for (int j = 0; j < 7; j++) w8[j] = f2bf(oh[j]);
            }
            *(u16x8*)&As[buf][ar * 64 + ((tq ^ (ar & 7)) * 8)] = w8;
            __syncthreads();
            bf16x8 a[4];
#pragma unroll
            for (int i = 0; i < 4; i++) {
                int row = i * 16 + lm;
                a[i] = *(const bf16x8*)&As[buf][row * 64 + ((lq ^ (row & 7)) * 8)];
            }
            // issue next-type B chunks 0,1
            if (t < 6) {
                int kb = (t + 1) * TSTRIDE;
                bcur[0][0] = *(const bf16x8*)&btp0[kb];
                bcur[0][1] = *(const bf16x8*)&btp1[kb];
                bcur[1][0] = *(const bf16x8*)&btp0[kb + 32];
                bcur[1][1] = *(const bf16x8*)&btp1[kb + 32];
            }
            __builtin_amdgcn_s_setprio(1);
#pragma unroll
            for (int i = 0; i < 4; i++) {
                acc[i][0] = __builtin_amdgcn_mfma_f32_16x16x32_bf16(a[i], boh[0], acc[i][0], 0, 0, 0);
                acc[i][1] = __builtin_amdgcn_mfma_f32_16x16x32_bf16(a[i], boh[1], acc[i][1], 0, 0, 0);
            }
            __builtin_amdgcn_s_setprio(0);
            // rotate next type -> current
            st = stn; en = enn;
#pragma unroll
            for (int u = 0; u < 4; u++) col[u] = coln[u];
            buf ^= 1;
        }
    }

    // ---- epilogue ----
#pragma unroll
    for (int i = 0; i < 4; i++) {
#pragma unroll
        for (int r = 0; r < 4; r++) {
            size_t m = (size_t)m0 + i * 16 + lq * 4 + r;
            float addv[2];
            if (mode == 0) {
                int b = batch_id[m];
#pragma unroll
                for (int j = 0; j < 2; j++) addv[j] = embout[b * 256 + wn * 32 + j * 16 + lm];
            } else {
#pragma unroll
                for (int j = 0; j < 2; j++) addv[j] = xres[m * 256 + wn * 32 + j * 16 + lm];
            }
#pragma unroll
            for (int j = 0; j < 2; j++) {
                int n = wn * 32 + j * 16 + lm;
                out[m * 256 + n] = acc[i][j][r] + addv[j];
            }
        }
    }
}

// ---------- host ----------
extern "C" void kernel_launch(void* const* d_in, const int* in_sizes, int n_in,
                              void* d_out, int out_size, void* d_ws, size_t ws_size,
                              hipStream_t stream) {
    const float* x    = (const float*)d_in[0];
    const float* emb  = (const float*)d_in[1];
    const int* bid    = (const int*)d_in[2];
    const int* ei     = (const int*)d_in[3];
    const int* et     = (const int*)d_in[4];
    const int* ntp    = (const int*)d_in[5];
    const float* gn1w = (const float*)d_in[6];
    const float* gn1b = (const float*)d_in[7];
    const float* w1   = (const float*)d_in[8];
    const float* embw = (const float*)d_in[9];
    const float* embb = (const float*)d_in[10];
    const float* gn2w = (const float*)d_in[11];
    const float* gn2b = (const float*)d_in[12];
    const float* w2   = (const float*)d_in[13];
    float* out = (float*)d_out;

    char* p = (char*)d_ws;
    size_t off = 0;
    auto nxt = [&](size_t bytes) -> void* {
        void* r = p + off;
        off += (bytes + 255) & ~(size_t)255;
        return r;
    };
    u16*   y       = (u16*)nxt((size_t)N_NODES * 256 * 2);     // 33.5 MB (bf16 stage)
    u16*   Wt1     = (u16*)nxt((size_t)256 * GK * 2);          // 1.03 MB
    u16*   Wt2     = (u16*)nxt((size_t)256 * GK * 2);          // 1.03 MB
    float* embout  = (float*)nxt(8 * 256 * 4);
    float* S       = (float*)nxt(2048 * 4);                    // S,Q,cnt contiguous
    float* Q       = (float*)nxt(2048 * 4);                    //   -> one memset
    int*   cnt     = (int*)nxt(8 * 4);
    int*   offs    = (int*)nxt((size_t)NSEG * 4);              // hist, then offsets in place
    int*   cursor  = (int*)nxt((size_t)NSEG * 4);
    int*   parts   = (int*)nxt(1024 * 4);
    int*   elist   = (int*)nxt((size_t)E_EDGES * 4);
    float* h2      = out;   // d_out doubles as h2 (dead before final write)
    (void)ws_size; (void)in_sizes; (void)n_in; (void)out_size;

    // zero scratch (graph-capture-safe async memsets)
    hipMemsetAsync(offs, 0, (size_t)NSEG * 4, stream);
    hipMemsetAsync(S, 0, 8192 + 8192 + 256, stream);           // S + Q + cnt
    // K1: count + weight transpose + emb GEMM + GN1 stats
    front_kernel<<<2289, 256, 0, stream>>>(bid, cnt, w1, w2, Wt1, Wt2,
                                           emb, embw, embb, embout, x, S, Q);
    // K2: hist + GN1 norm/SiLU (inline finalize) -> y
    hist_norm_kernel<<<9984, 256, 0, stream>>>(ei, et, offs, x, bid, S, Q, cnt, gn1w, gn1b, y);
    // K3-K5: CSR scans
    scan1_kernel<<<896, 512, 0, stream>>>(offs, parts);
    scan2_kernel<<<1, 1024, 0, stream>>>(parts);
    scan3_kernel<<<896, 512, 0, stream>>>(offs, parts, cursor);
    // K6: fill elist + re-zero S/Q
    fill_zero_kernel<<<1800, 256, 0, stream>>>(ei, et, cursor, elist, S, Q);
    // K7: conv1 fused aggregate+GEMM(+emb) -> h2 (in d_out)
    gemm_fused_kernel<<<1024, 512, 0, stream>>>(y, Wt1, offs, cursor, elist, ntp, bid, embout, x, h2, 0);
    // K8-K9: GN2 stats + norm/SiLU -> y
    stats_kernel<<<1024, 256, 0, stream>>>(h2, bid, S, Q);
    norm_kernel<<<8192, 256, 0, stream>>>(h2, bid, S, Q, cnt, gn2w, gn2b, y);
    // K10: conv2 fused aggregate+GEMM(+x skip) -> out
    gemm_fused_kernel<<<1024, 512, 0, stream>>>(y, Wt2, offs, cursor, elist, ntp, bid, embout, x, out, 1);
}